// Round 9
// baseline (156.149 us; speedup 1.0000x reference)
//
#include <hip/hip_runtime.h>
#include <hip/hip_bf16.h>

typedef unsigned short u16;
typedef __bf16 bf16x8 __attribute__((ext_vector_type(8)));
typedef float f32x4 __attribute__((ext_vector_type(4)));
typedef unsigned short u16x8 __attribute__((ext_vector_type(8)));
typedef unsigned short u16x4 __attribute__((ext_vector_type(4)));

__device__ __forceinline__ float bf2f(u16 u) {
  unsigned int x = ((unsigned int)u) << 16;
  return __builtin_bit_cast(float, x);
}
__device__ __forceinline__ u16 f2bf(float f) {
  unsigned int x = __builtin_bit_cast(unsigned int, f);
  x = x + 0x7FFFu + ((x >> 16) & 1u);
  return (u16)(x >> 16);
}

// async global->LDS, 16B per lane; LDS dest is wave-uniform base + lane*16.
__device__ __forceinline__ void gload_lds16(const u16* g, u16* l) {
  __builtin_amdgcn_global_load_lds(
      (const __attribute__((address_space(1))) unsigned int*)(unsigned long long)(uintptr_t)g,
      (__attribute__((address_space(3))) unsigned int*)(unsigned int)(uintptr_t)l,
      16, 0, 0);
}

// ---------------- prep: cast X fp32->bf16  UNION  transpose+cast W ----------------
// id < 4096: cast 8 elems of X. id >= 4096: one 64x64 transpose tile of Wq/Wk/Wv
// (768 tiles: z = t>>8 picks W, 1/sqrt(1024) folded into Wq).
__global__ __launch_bounds__(256) void prep_kernel(const float* __restrict__ X,
                                                   const float* __restrict__ Wq,
                                                   const float* __restrict__ Wk,
                                                   const float* __restrict__ Wv,
                                                   u16* __restrict__ Xb,
                                                   u16* __restrict__ Wt) {
  const int id = blockIdx.x;
  const int tid = threadIdx.x;
  if (id < 4096) {
    long i = ((long)id * 256 + tid) * 8;
    float4 a = *reinterpret_cast<const float4*>(X + i);
    float4 b = *reinterpret_cast<const float4*>(X + i + 4);
    u16x8 o;
    o[0] = f2bf(a.x); o[1] = f2bf(a.y); o[2] = f2bf(a.z); o[3] = f2bf(a.w);
    o[4] = f2bf(b.x); o[5] = f2bf(b.y); o[6] = f2bf(b.z); o[7] = f2bf(b.w);
    *reinterpret_cast<u16x8*>(Xb + i) = o;
    return;
  }
  __shared__ u16 t[64][72];
  const int id2 = id - 4096;
  const int z = id2 >> 8;
  const float* W = (z == 0) ? Wq : (z == 1) ? Wk : Wv;
  const float scale = (z == 0) ? (1.0f / 32.0f) : 1.0f;
  u16* out = Wt + (long)z * 1048576;
  const int c0 = (id2 & 15) * 64;        // n dim
  const int r0 = ((id2 >> 4) & 15) * 64; // k dim
#pragma unroll
  for (int i = 0; i < 4; ++i) {
    int slot = tid + 256 * i;
    int lr = slot >> 4;
    int lc4 = slot & 15;
    float4 v = *reinterpret_cast<const float4*>(W + (long)(r0 + lr) * 1024 + c0 + lc4 * 4);
    t[lr][lc4 * 4 + 0] = f2bf(v.x * scale);
    t[lr][lc4 * 4 + 1] = f2bf(v.y * scale);
    t[lr][lc4 * 4 + 2] = f2bf(v.z * scale);
    t[lr][lc4 * 4 + 3] = f2bf(v.w * scale);
  }
  __syncthreads();
#pragma unroll
  for (int i = 0; i < 2; ++i) {
    int slot = tid + 256 * i;
    int orow = slot >> 3;
    int oc = slot & 7;
    u16x8 o;
#pragma unroll
    for (int j = 0; j < 8; ++j) o[j] = t[oc * 8 + j][orow];
    *reinterpret_cast<u16x8*>(out + (long)(c0 + orow) * 1024 + r0 + oc * 8) = o;
  }
}

// ---------------- NT GEMM core: C[M][N] = sum_k A[m][k] * B[n][k] ----------------
// 128x128 tile, 4 waves (2x2 of 64x64), BK=64, global_load_lds width-16 staging.
// Double-buffered LDS, one __syncthreads per K-step (r5 structure — counted
// vmcnt (r6) and 8-phase 256^2 (r7) both measured neutral/regression here).
// LDS: linear dest + PRE-SWIZZLED global source + XOR-swizzled ds_read.
// MFMA operands SWAPPED (D rows = N-dim) -> vectorized C stores, except
// V-projection blocks (normal order; transposed Vt store vectorizes along M).
// __launch_bounds__(256,2): (256,4) forced VGPR<=64 -> acc scratch spill (r3).
// Softmax fused away (r8): |scores| <= 32 so exp needs no max-subtraction.
// DISPATCH PACKING (r9): V-projection is independent of S, so its 512 blocks
// ride in the S dispatch and fill the triangle's idle slots (544+512 = 2.06
// rounds vs 1.06-rounds-paying-2 before).
// MODE 0: QK projection. grid 1024 (= exactly 2 rounds). Q,K bf16 [8192][1024].
// MODE 1: id<512: V-proj (A2=Xb, B2=WtV) -> Vt[b][1024][2048] transposed.
//         id>=512: P = exp(Q K^T) triangle tile, bf16 + row-sum atomics.
// MODE 2: O = P V / rowsum per batch. grid (8,16,4), kEnd=m0+128, f32 out.
template <int MODE>
__global__ __launch_bounds__(256, 2) void gemm_nt(const u16* __restrict__ Ag,
                                                  const u16* __restrict__ Bg,
                                                  void* __restrict__ Cg,
                                                  float* __restrict__ Sums,
                                                  const u16* __restrict__ A2,
                                                  const u16* __restrict__ B2,
                                                  u16* __restrict__ C2,
                                                  int K, long sA, long sB, long sC) {
  int bm, bn, bz = 0;
  bool vblk = false;
  const u16* A;
  const u16* B;
  if constexpr (MODE == 0) {
    const int id = blockIdx.x;            // 0..1023
    const int xcd = id & 7, j = id >> 3;  // j: 0..127
    bn = (xcd & 1) * 8 + (j & 7);         // 0..15
    bm = (xcd >> 1) * 16 + (j >> 3);      // 0..63
    A = Ag; B = Bg;
  } else if constexpr (MODE == 1) {
    const int id = blockIdx.x;            // 0..1055
    if (id < 512) {                       // V-projection
      vblk = true;
      const int xcd = id & 7, j = id >> 3;
      bm = xcd * 8 + (j >> 3);            // 0..63
      bn = j & 7;                         // 0..7
      A = A2; B = B2;
    } else {                              // S triangle
      int t = id - 512;                   // 0..543
      bz = t / 136; t -= bz * 136;
      int r = 0;
      while ((r + 1) * (r + 2) / 2 <= t) ++r;
      bm = r; bn = t - r * (r + 1) / 2;
      A = Ag + (long)bz * sA; B = Bg + (long)bz * sB;
    }
  } else {
    const int id = blockIdx.y * 8 + blockIdx.x;   // 0..127
    const int xcd = id & 7, j = id >> 3;
    bn = j & 7;
    bm = (j >> 3) ? (15 - xcd) : xcd;     // balanced: work ∝ bm+1
    bz = blockIdx.z;
    A = Ag + (long)bz * sA; B = Bg + (long)bz * sB;
  }

  const int m0 = bm * 128, n0 = bn * 128;
  int kEnd = K;
  if constexpr (MODE == 2) kEnd = m0 + 128;  // causal k-limit

  __shared__ u16 ldsA[2][8192];
  __shared__ u16 ldsB[2][8192];

  const int tid = threadIdx.x;
  const int lane = tid & 63;
  const int wid = tid >> 6;
  const int wm = wid >> 1, wn = wid & 1;
  const int l16 = lane & 15, lh = lane >> 4;
  const int srow = lane >> 3;
  const int scol = ((lane & 7) ^ srow) * 8;  // pre-swizzled source column
  const int rsw = l16 & 7;                   // read-side swizzle key

  f32x4 acc[4][4];
#pragma unroll
  for (int mi = 0; mi < 4; ++mi)
#pragma unroll
    for (int ni = 0; ni < 4; ++ni) acc[mi][ni] = (f32x4)(0.0f);

  auto stage = [&](int d, int k0) {
#pragma unroll
    for (int s = 0; s < 4; ++s) {
      const int seg = wid * 4 + s;           // 0..15 (1KB segments)
      const int row = seg * 8 + srow;        // 0..127
      gload_lds16(A + (long)(m0 + row) * K + k0 + scol, &ldsA[d][seg * 512]);
      gload_lds16(B + (long)(n0 + row) * K + k0 + scol, &ldsB[d][seg * 512]);
    }
  };

  stage(0, 0);
  int cur = 0;
  for (int k0 = 0; k0 < kEnd; k0 += 64) {
    __syncthreads();                         // buf[cur] ready; old readers of buf^1 done
    if (k0 + 64 < kEnd) stage(cur ^ 1, k0 + 64);  // lands during compute below
#pragma unroll
    for (int kk = 0; kk < 2; ++kk) {
      bf16x8 af[4], bfr[4];
#pragma unroll
      for (int mi = 0; mi < 4; ++mi)
        af[mi] = *reinterpret_cast<const bf16x8*>(
            &ldsA[cur][(wm * 64 + mi * 16 + l16) * 64 + (((kk * 4 + lh) ^ rsw)) * 8]);
#pragma unroll
      for (int ni = 0; ni < 4; ++ni)
        bfr[ni] = *reinterpret_cast<const bf16x8*>(
            &ldsB[cur][(wn * 64 + ni * 16 + l16) * 64 + (((kk * 4 + lh) ^ rsw)) * 8]);
      if (!vblk) {
#pragma unroll
        for (int mi = 0; mi < 4; ++mi)
#pragma unroll
          for (int ni = 0; ni < 4; ++ni)
            acc[mi][ni] = __builtin_amdgcn_mfma_f32_16x16x32_bf16(bfr[ni], af[mi], acc[mi][ni], 0, 0, 0);
      } else {
#pragma unroll
        for (int mi = 0; mi < 4; ++mi)
#pragma unroll
          for (int ni = 0; ni < 4; ++ni)
            acc[mi][ni] = __builtin_amdgcn_mfma_f32_16x16x32_bf16(af[mi], bfr[ni], acc[mi][ni], 0, 0, 0);
      }
    }
    cur ^= 1;
  }

  // Swapped layout: element C[m0+wm*64+mi*16+l16][n0+wn*64+ni*16+lh*4+r] = acc[mi][ni][r]
  if constexpr (MODE == 0) {
    const int z = bn >> 3;               // 0=Q, 1=K
    const int colbase = (bn & 7) * 128;
    u16* C = (u16*)Cg + (long)z * 8388608;
    const long rown = (long)(m0 + wm * 64 + l16);
    const int coln = colbase + wn * 64 + lh * 4;
#pragma unroll
    for (int mi = 0; mi < 4; ++mi)
#pragma unroll
      for (int ni = 0; ni < 4; ++ni) {
        u16x4 o;
#pragma unroll
        for (int r = 0; r < 4; ++r) o[r] = f2bf(acc[mi][ni][r]);
        *reinterpret_cast<u16x4*>(&C[(rown + mi * 16) * 1024 + coln + ni * 16]) = o;
      }
  } else if constexpr (MODE == 1) {
    if (vblk) {
      // V (normal order): D row = M-dim(t). Vt[b][e][t], vector along t.
      const int b = m0 >> 11;
      const int t0 = (m0 & 2047) + wm * 64 + lh * 4;
      const int e0 = bn * 128 + wn * 64 + l16;
#pragma unroll
      for (int mi = 0; mi < 4; ++mi)
#pragma unroll
        for (int ni = 0; ni < 4; ++ni) {
          u16x4 o;
#pragma unroll
          for (int r = 0; r < 4; ++r) o[r] = f2bf(acc[mi][ni][r]);
          *reinterpret_cast<u16x4*>(
              &C2[(long)b * 2097152 + (long)(e0 + ni * 16) * 2048 + t0 + mi * 16]) = o;
        }
    } else {
      // P = exp(S), zero above diagonal; row sums from bf16-rounded values so
      // numerator/denominator agree. shfl over lh then 1 atomic per 16 lanes.
      u16* C = (u16*)Cg + (long)bz * sC;
      float* sums = Sums + (long)bz * 2048;
      const long rown = (long)(m0 + wm * 64 + l16);
      const int coln = n0 + wn * 64 + lh * 4;
#pragma unroll
      for (int mi = 0; mi < 4; ++mi) {
        const int gr = m0 + wm * 64 + l16 + mi * 16;
        float rs = 0.0f;
#pragma unroll
        for (int ni = 0; ni < 4; ++ni) {
          u16x4 o;
#pragma unroll
          for (int r = 0; r < 4; ++r) {
            const int gc = coln + ni * 16 + r;
            const float e = (gc <= gr) ? __expf(acc[mi][ni][r]) : 0.0f;
            const u16 ub = f2bf(e);
            o[r] = ub;
            rs += bf2f(ub);
          }
          *reinterpret_cast<u16x4*>(&C[(rown + mi * 16) * 2048 + coln + ni * 16]) = o;
        }
        rs += __shfl_xor(rs, 16);
        rs += __shfl_xor(rs, 32);
        if (lh == 0) atomicAdd(&sums[gr], rs);
      }
    }
  } else {
    // O = acc / rowsum
    float* C = (float*)Cg + (long)bz * sC;
    const float* sums = Sums + (long)bz * 2048;
    const long rown = (long)(m0 + wm * 64 + l16);
    const int coln = n0 + wn * 64 + lh * 4;
#pragma unroll
    for (int mi = 0; mi < 4; ++mi) {
      const float inv = 1.0f / sums[(int)rown + mi * 16];
#pragma unroll
      for (int ni = 0; ni < 4; ++ni) {
        f32x4 v = acc[mi][ni] * inv;
        *reinterpret_cast<f32x4*>(&C[(rown + mi * 16) * 1024 + coln + ni * 16]) = v;
      }
    }
  }
}

extern "C" void kernel_launch(void* const* d_in, const int* in_sizes, int n_in,
                              void* d_out, int out_size, void* d_ws, size_t ws_size,
                              hipStream_t stream) {
  const float* X  = (const float*)d_in[0];
  const float* Wq = (const float*)d_in[1];
  const float* Wk = (const float*)d_in[2];
  const float* Wv = (const float*)d_in[3];

  // workspace layout (u16 elements)
  u16* Xb = (u16*)d_ws;                 // 8192*1024
  u16* Wt = Xb + 8388608;               // [3072][1024]; Wq rows pre-scaled 1/32
  u16* Qb = Wt + 3145728;               // 8192*1024
  u16* Kb = Qb + 8388608;               // 8192*1024
  u16* Vt = Kb + 8388608;               // [b][1024][2048]
  u16* S  = Vt + 8388608;               // [b][2048][2048] -> holds P = exp(scores)
  float* sums = (float*)(S + 16777216); // [b][2048] row sums (32 KB)

  hipMemsetAsync(sums, 0, 4 * 2048 * sizeof(float), stream);

  // cast X + transpose W (one dispatch)
  prep_kernel<<<4864, 256, 0, stream>>>(X, Wq, Wk, Wv, Xb, Wt);

  // QK projection (1024 blocks = exactly 2 rounds at 2 blocks/CU)
  gemm_nt<0><<<1024, 256, 0, stream>>>(Xb, Wt, Qb, nullptr,
                                       nullptr, nullptr, nullptr, 1024, 0L, 0L, 0L);

  // V projection (512 blocks) packed with P = exp(Q K^T) triangle (544 blocks)
  gemm_nt<1><<<1056, 256, 0, stream>>>(Qb, Kb, S, sums,
                                       Xb, Wt + 2097152, Vt,
                                       1024, 2097152L, 2097152L, 4194304L);

  // O = P V / rowsum per batch
  gemm_nt<2><<<dim3(8, 16, 4), 256, 0, stream>>>(S, Vt, (float*)d_out, sums,
                                                 nullptr, nullptr, nullptr,
                                                 2048, 4194304L, 2097152L, 2097152L);
}

// Round 10
// 145.764 us; speedup vs baseline: 1.0712x; 1.0712x over previous
//
#include <hip/hip_runtime.h>
#include <hip/hip_bf16.h>

typedef unsigned short u16;
typedef __bf16 bf16x8 __attribute__((ext_vector_type(8)));
typedef float f32x4 __attribute__((ext_vector_type(4)));
typedef unsigned short u16x8 __attribute__((ext_vector_type(8)));
typedef unsigned short u16x4 __attribute__((ext_vector_type(4)));

__device__ __forceinline__ float bf2f(u16 u) {
  unsigned int x = ((unsigned int)u) << 16;
  return __builtin_bit_cast(float, x);
}
__device__ __forceinline__ u16 f2bf(float f) {
  unsigned int x = __builtin_bit_cast(unsigned int, f);
  x = x + 0x7FFFu + ((x >> 16) & 1u);
  return (u16)(x >> 16);
}

// async global->LDS, 16B per lane; LDS dest is wave-uniform base + lane*16.
__device__ __forceinline__ void gload_lds16(const u16* g, u16* l) {
  __builtin_amdgcn_global_load_lds(
      (const __attribute__((address_space(1))) unsigned int*)(unsigned long long)(uintptr_t)g,
      (__attribute__((address_space(3))) unsigned int*)(unsigned int)(uintptr_t)l,
      16, 0, 0);
}

// ---------------- prep: cast X fp32->bf16  UNION  transpose+cast W ----------------
__global__ __launch_bounds__(256) void prep_kernel(const float* __restrict__ X,
                                                   const float* __restrict__ Wq,
                                                   const float* __restrict__ Wk,
                                                   const float* __restrict__ Wv,
                                                   u16* __restrict__ Xb,
                                                   u16* __restrict__ Wt) {
  const int id = blockIdx.x;
  const int tid = threadIdx.x;
  if (id < 4096) {
    long i = ((long)id * 256 + tid) * 8;
    float4 a = *reinterpret_cast<const float4*>(X + i);
    float4 b = *reinterpret_cast<const float4*>(X + i + 4);
    u16x8 o;
    o[0] = f2bf(a.x); o[1] = f2bf(a.y); o[2] = f2bf(a.z); o[3] = f2bf(a.w);
    o[4] = f2bf(b.x); o[5] = f2bf(b.y); o[6] = f2bf(b.z); o[7] = f2bf(b.w);
    *reinterpret_cast<u16x8*>(Xb + i) = o;
    return;
  }
  __shared__ u16 t[64][72];
  const int id2 = id - 4096;
  const int z = id2 >> 8;
  const float* W = (z == 0) ? Wq : (z == 1) ? Wk : Wv;
  const float scale = (z == 0) ? (1.0f / 32.0f) : 1.0f;  // fold 1/sqrt(1024) into Wq
  u16* out = Wt + (long)z * 1048576;
  const int c0 = (id2 & 15) * 64;
  const int r0 = ((id2 >> 4) & 15) * 64;
#pragma unroll
  for (int i = 0; i < 4; ++i) {
    int slot = tid + 256 * i;
    int lr = slot >> 4;
    int lc4 = slot & 15;
    float4 v = *reinterpret_cast<const float4*>(W + (long)(r0 + lr) * 1024 + c0 + lc4 * 4);
    t[lr][lc4 * 4 + 0] = f2bf(v.x * scale);
    t[lr][lc4 * 4 + 1] = f2bf(v.y * scale);
    t[lr][lc4 * 4 + 2] = f2bf(v.z * scale);
    t[lr][lc4 * 4 + 3] = f2bf(v.w * scale);
  }
  __syncthreads();
#pragma unroll
  for (int i = 0; i < 2; ++i) {
    int slot = tid + 256 * i;
    int orow = slot >> 3;
    int oc = slot & 7;
    u16x8 o;
#pragma unroll
    for (int j = 0; j < 8; ++j) o[j] = t[oc * 8 + j][orow];
    *reinterpret_cast<u16x8*>(out + (long)(c0 + orow) * 1024 + r0 + oc * 8) = o;
  }
}

// ---------------- NT GEMM core: C[M][N] = sum_k A[m][k] * B[n][k] ----------------
// r10: 8-WAVE blocks (512 thr) on the same 128x128 tile — occupancy lever.
// r8 ran 4-wave blocks: 2 blocks/CU = 8 waves/CU, MfmaUtil 32%, VALU 23%,
// HBM <=20%, Occ 18% -> latency-bound (G1). Same 64KB LDS now hosts 8 waves
// -> 16 waves/CU resident. Wave tile 64x32 (acc[4][2], ~32 acc VGPR; no spill
// at __launch_bounds__(512,2) — r3 lesson).
// Everything else identical to r8: BK=64, dbuf LDS, one __syncthreads per
// K-step with stage issued right after the barrier (r5 structure; counted
// vmcnt (r6) and 8-phase 256^2 (r7) measured neutral/regression here);
// linear LDS dest + pre-swizzled global source + XOR-swizzled ds_read;
// swapped MFMA operands (D rows = N) for vectorized stores, except V blocks.
// Softmax fused away (r8): |scores| <= 32, exp needs no max-subtraction.
// Dispatch packing = r8 (r9's V+S packing regressed: equal blocks are
// work-conserving, packing fills nothing; and it thrashed L2).
// MODE 0: fused QKV. grid 1536. Q,K -> bf16 [8192][1024]; V -> Vt[b][1024][2048].
// MODE 1: P = exp(Q K^T) per batch. grid (16,16,4), skip bn>bm, bf16 + row sums.
// MODE 2: O = P V / rowsum per batch. grid (8,16,4), kEnd=m0+128, f32 out.
template <int MODE>
__global__ __launch_bounds__(512, 2) void gemm_nt(const u16* __restrict__ Ag,
                                                  const u16* __restrict__ Bg,
                                                  void* __restrict__ Cg,
                                                  float* __restrict__ Sums,
                                                  int K, long sA, long sB, long sC) {
  int bm, bn, bz;
  if constexpr (MODE == 0) {
    const int id = blockIdx.x;           // 0..1535
    const int xcd = id & 7, j = id >> 3; // j: 0..191
    const int cx = xcd & 1, cy = xcd >> 1;
    bn = cx * 12 + j % 12;               // 0..23
    bm = cy * 16 + j / 12;               // 0..63
    bz = 0;
  } else if constexpr (MODE == 1) {
    const int id = blockIdx.y * 16 + blockIdx.x;  // 0..255
    const int xcd = id & 7, j = id >> 3;
    bn = j & 15;
    bm = (j >> 4) ? (15 - xcd) : xcd;    // rows (x,15-x): balanced triangle
    bz = blockIdx.z;
    if (bn > bm) return;
  } else {
    const int id = blockIdx.y * 8 + blockIdx.x;   // 0..127
    const int xcd = id & 7, j = id >> 3;
    bn = j & 7;
    bm = (j >> 3) ? (15 - xcd) : xcd;    // balanced: work ∝ bm+1
    bz = blockIdx.z;
  }

  const u16* A = Ag + (long)bz * sA;
  const u16* B = Bg + (long)bz * sB;
  const int m0 = bm * 128, n0 = bn * 128;
  int kEnd = K;
  if constexpr (MODE == 2) kEnd = m0 + 128;  // causal k-limit

  __shared__ u16 ldsA[2][8192];
  __shared__ u16 ldsB[2][8192];

  const int tid = threadIdx.x;          // 0..511
  const int lane = tid & 63;
  const int wid = tid >> 6;             // 0..7
  const int wm = wid >> 2, wn = wid & 3;
  const int l16 = lane & 15, lh = lane >> 4;
  const int strow = tid >> 3;                       // 0..63 (staging row within issue)
  const int scol = ((tid & 7) ^ (strow & 7)) * 8;   // pre-swizzled source column
  const int rsw = l16 & 7;                          // read-side swizzle key

  bool vblk = false;                    // V-quadrant: normal operand order
  if constexpr (MODE == 0) vblk = ((bn >> 3) == 2);

  f32x4 acc[4][2];
#pragma unroll
  for (int mi = 0; mi < 4; ++mi)
#pragma unroll
    for (int ni = 0; ni < 2; ++ni) acc[mi][ni] = (f32x4)(0.0f);

  // stage tile at k0 into buffer d: 512 thr x 16B = 8KB/issue; 2 issues each
  // for A and B. LDS offset = l*8192B + tid*16B (linear, wave-uniform base).
  auto stage = [&](int d, int k0) {
#pragma unroll
    for (int l = 0; l < 2; ++l) {
      const int row = l * 64 + strow;   // 0..127
      gload_lds16(A + (long)(m0 + row) * K + k0 + scol, &ldsA[d][l * 4096 + tid * 8]);
      gload_lds16(B + (long)(n0 + row) * K + k0 + scol, &ldsB[d][l * 4096 + tid * 8]);
    }
  };

  stage(0, 0);
  int cur = 0;
  for (int k0 = 0; k0 < kEnd; k0 += 64) {
    __syncthreads();                         // buf[cur] ready; old readers of buf^1 done
    if (k0 + 64 < kEnd) stage(cur ^ 1, k0 + 64);  // lands during compute below
#pragma unroll
    for (int kk = 0; kk < 2; ++kk) {
      bf16x8 af[4], bfr[2];
#pragma unroll
      for (int mi = 0; mi < 4; ++mi)
        af[mi] = *reinterpret_cast<const bf16x8*>(
            &ldsA[cur][(wm * 64 + mi * 16 + l16) * 64 + (((kk * 4 + lh) ^ rsw)) * 8]);
#pragma unroll
      for (int ni = 0; ni < 2; ++ni)
        bfr[ni] = *reinterpret_cast<const bf16x8*>(
            &ldsB[cur][(wn * 32 + ni * 16 + l16) * 64 + (((kk * 4 + lh) ^ rsw)) * 8]);
      if (!vblk) {
#pragma unroll
        for (int mi = 0; mi < 4; ++mi)
#pragma unroll
          for (int ni = 0; ni < 2; ++ni)
            acc[mi][ni] = __builtin_amdgcn_mfma_f32_16x16x32_bf16(bfr[ni], af[mi], acc[mi][ni], 0, 0, 0);
      } else {
#pragma unroll
        for (int mi = 0; mi < 4; ++mi)
#pragma unroll
          for (int ni = 0; ni < 2; ++ni)
            acc[mi][ni] = __builtin_amdgcn_mfma_f32_16x16x32_bf16(af[mi], bfr[ni], acc[mi][ni], 0, 0, 0);
      }
    }
    cur ^= 1;
  }

  // Swapped layout: C[m0+wm*64+mi*16+l16][n0+wn*32+ni*16+lh*4+r] = acc[mi][ni][r]
  if constexpr (MODE == 0) {
    const int z = bn >> 3;               // 0=Q, 1=K, 2=V
    const int colbase = (bn & 7) * 128;
    if (z < 2) {
      u16* C = (u16*)Cg + (long)z * 8388608;
      const long rown = (long)(m0 + wm * 64 + l16);
      const int coln = colbase + wn * 32 + lh * 4;
#pragma unroll
      for (int mi = 0; mi < 4; ++mi)
#pragma unroll
        for (int ni = 0; ni < 2; ++ni) {
          u16x4 o;
#pragma unroll
          for (int r = 0; r < 4; ++r) o[r] = f2bf(acc[mi][ni][r]);
          *reinterpret_cast<u16x4*>(&C[(rown + mi * 16) * 1024 + coln + ni * 16]) = o;
        }
    } else {
      // V (normal order): D row = M-dim(t). Vt[b][e][t], vector along t.
      u16* C = (u16*)Cg + 16777216;      // Vt base
      const int b = m0 >> 11;
      const int t0 = (m0 & 2047) + wm * 64 + lh * 4;
      const int e0 = colbase + wn * 32 + l16;
#pragma unroll
      for (int mi = 0; mi < 4; ++mi)
#pragma unroll
        for (int ni = 0; ni < 2; ++ni) {
          u16x4 o;
#pragma unroll
          for (int r = 0; r < 4; ++r) o[r] = f2bf(acc[mi][ni][r]);
          *reinterpret_cast<u16x4*>(
              &C[(long)b * 2097152 + (long)(e0 + ni * 16) * 2048 + t0 + mi * 16]) = o;
        }
    }
  } else if constexpr (MODE == 1) {
    // P = exp(S), zero above diagonal; row sums from bf16-rounded values so
    // numerator/denominator agree. shfl over lh then 1 atomic per 16 lanes.
    u16* C = (u16*)Cg + (long)bz * sC;
    float* sums = Sums + (long)bz * 2048;
    const long rown = (long)(m0 + wm * 64 + l16);
    const int coln = n0 + wn * 32 + lh * 4;
#pragma unroll
    for (int mi = 0; mi < 4; ++mi) {
      const int gr = m0 + wm * 64 + l16 + mi * 16;
      float rs = 0.0f;
#pragma unroll
      for (int ni = 0; ni < 2; ++ni) {
        u16x4 o;
#pragma unroll
        for (int r = 0; r < 4; ++r) {
          const int gc = coln + ni * 16 + r;
          const float e = (gc <= gr) ? __expf(acc[mi][ni][r]) : 0.0f;
          const u16 ub = f2bf(e);
          o[r] = ub;
          rs += bf2f(ub);
        }
        *reinterpret_cast<u16x4*>(&C[(rown + mi * 16) * 2048 + coln + ni * 16]) = o;
      }
      rs += __shfl_xor(rs, 16);
      rs += __shfl_xor(rs, 32);
      if (lh == 0) atomicAdd(&sums[gr], rs);
    }
  } else {
    // O = acc / rowsum
    float* C = (float*)Cg + (long)bz * sC;
    const float* sums = Sums + (long)bz * 2048;
    const long rown = (long)(m0 + wm * 64 + l16);
    const int coln = n0 + wn * 32 + lh * 4;
#pragma unroll
    for (int mi = 0; mi < 4; ++mi) {
      const float inv = 1.0f / sums[(int)rown + mi * 16];
#pragma unroll
      for (int ni = 0; ni < 2; ++ni) {
        f32x4 v = acc[mi][ni] * inv;
        *reinterpret_cast<f32x4*>(&C[(rown + mi * 16) * 1024 + coln + ni * 16]) = v;
      }
    }
  }
}

extern "C" void kernel_launch(void* const* d_in, const int* in_sizes, int n_in,
                              void* d_out, int out_size, void* d_ws, size_t ws_size,
                              hipStream_t stream) {
  const float* X  = (const float*)d_in[0];
  const float* Wq = (const float*)d_in[1];
  const float* Wk = (const float*)d_in[2];
  const float* Wv = (const float*)d_in[3];

  // workspace layout (u16 elements)
  u16* Xb = (u16*)d_ws;                 // 8192*1024
  u16* Wt = Xb + 8388608;               // [3072][1024]; Wq rows pre-scaled 1/32
  u16* Qb = Wt + 3145728;               // 8192*1024
  u16* Kb = Qb + 8388608;               // 8192*1024
  u16* Vt = Kb + 8388608;               // [b][1024][2048]
  u16* S  = Vt + 8388608;               // [b][2048][2048] -> holds P = exp(scores)
  float* sums = (float*)(S + 16777216); // [b][2048] row sums (32 KB)

  hipMemsetAsync(sums, 0, 4 * 2048 * sizeof(float), stream);

  // cast X + transpose W (one dispatch)
  prep_kernel<<<4864, 256, 0, stream>>>(X, Wq, Wk, Wv, Xb, Wt);

  // fused QKV projection (V written transposed)
  gemm_nt<0><<<1536, 512, 0, stream>>>(Xb, Wt, Qb, nullptr, 1024, 0L, 0L, 0L);

  // P = exp(Q K^T) per batch (Q pre-scaled; causal zeros; row sums via atomics)
  gemm_nt<1><<<dim3(16, 16, 4), 512, 0, stream>>>(
      Qb, Kb, S, sums, 1024, 2097152L, 2097152L, 4194304L);

  // O = P V / rowsum per batch
  gemm_nt<2><<<dim3(8, 16, 4), 512, 0, stream>>>(
      S, Vt, (float*)d_out, sums, 2048, 4194304L, 2097152L, 2097152L);
}

// Round 11
// 138.992 us; speedup vs baseline: 1.1234x; 1.0487x over previous
//
#include <hip/hip_runtime.h>
#include <hip/hip_bf16.h>

typedef unsigned short u16;
typedef __bf16 bf16x8 __attribute__((ext_vector_type(8)));
typedef float f32x4 __attribute__((ext_vector_type(4)));
typedef unsigned short u16x8 __attribute__((ext_vector_type(8)));
typedef unsigned short u16x4 __attribute__((ext_vector_type(4)));

__device__ __forceinline__ float bf2f(u16 u) {
  unsigned int x = ((unsigned int)u) << 16;
  return __builtin_bit_cast(float, x);
}
__device__ __forceinline__ u16 f2bf(float f) {
  unsigned int x = __builtin_bit_cast(unsigned int, f);
  x = x + 0x7FFFu + ((x >> 16) & 1u);
  return (u16)(x >> 16);
}

// async global->LDS, 16B per lane; LDS dest is wave-uniform base + lane*16.
__device__ __forceinline__ void gload_lds16(const u16* g, u16* l) {
  __builtin_amdgcn_global_load_lds(
      (const __attribute__((address_space(1))) unsigned int*)(unsigned long long)(uintptr_t)g,
      (__attribute__((address_space(3))) unsigned int*)(unsigned int)(uintptr_t)l,
      16, 0, 0);
}

// ---------------- prep: cast X fp32->bf16  UNION  transpose+cast W ----------------
__global__ __launch_bounds__(256) void prep_kernel(const float* __restrict__ X,
                                                   const float* __restrict__ Wq,
                                                   const float* __restrict__ Wk,
                                                   const float* __restrict__ Wv,
                                                   u16* __restrict__ Xb,
                                                   u16* __restrict__ Wt) {
  const int id = blockIdx.x;
  const int tid = threadIdx.x;
  if (id < 4096) {
    long i = ((long)id * 256 + tid) * 8;
    float4 a = *reinterpret_cast<const float4*>(X + i);
    float4 b = *reinterpret_cast<const float4*>(X + i + 4);
    u16x8 o;
    o[0] = f2bf(a.x); o[1] = f2bf(a.y); o[2] = f2bf(a.z); o[3] = f2bf(a.w);
    o[4] = f2bf(b.x); o[5] = f2bf(b.y); o[6] = f2bf(b.z); o[7] = f2bf(b.w);
    *reinterpret_cast<u16x8*>(Xb + i) = o;
    return;
  }
  __shared__ u16 t[64][72];
  const int id2 = id - 4096;
  const int z = id2 >> 8;
  const float* W = (z == 0) ? Wq : (z == 1) ? Wk : Wv;
  const float scale = (z == 0) ? (1.0f / 32.0f) : 1.0f;  // fold 1/sqrt(1024) into Wq
  u16* out = Wt + (long)z * 1048576;
  const int c0 = (id2 & 15) * 64;
  const int r0 = ((id2 >> 4) & 15) * 64;
#pragma unroll
  for (int i = 0; i < 4; ++i) {
    int slot = tid + 256 * i;
    int lr = slot >> 4;
    int lc4 = slot & 15;
    float4 v = *reinterpret_cast<const float4*>(W + (long)(r0 + lr) * 1024 + c0 + lc4 * 4);
    t[lr][lc4 * 4 + 0] = f2bf(v.x * scale);
    t[lr][lc4 * 4 + 1] = f2bf(v.y * scale);
    t[lr][lc4 * 4 + 2] = f2bf(v.z * scale);
    t[lr][lc4 * 4 + 3] = f2bf(v.w * scale);
  }
  __syncthreads();
#pragma unroll
  for (int i = 0; i < 2; ++i) {
    int slot = tid + 256 * i;
    int orow = slot >> 3;
    int oc = slot & 7;
    u16x8 o;
#pragma unroll
    for (int j = 0; j < 8; ++j) o[j] = t[oc * 8 + j][orow];
    *reinterpret_cast<u16x8*>(out + (long)(c0 + orow) * 1024 + r0 + oc * 8) = o;
  }
}

// ---------------- fused QKV projection, 128x192 tile (r11) ----------------
// r5..r10 post-mortem: the 64x32 wave tile is LDS-READ-ROOFLINE-bound:
// 128*128*64*2 FLOP per 96KB ds_read = 10.9 FLOP/B * 69 TB/s = 750 TF —
// exactly the measured plateau. Fix = geometry: block 128x192, 8 waves of
// 64x48 (acc[4][3]) -> 27.4 FLOP/B (1.9 PF LDS ceiling, not binding).
// LDS (16+24)KB * 2 dbuf = 80KB -> still 2 blocks/CU (the overlap that hides
// the barrier drain). Grid 64x16 = 1024 blocks = EXACTLY 2 rounds (was 3).
// Same proven schedule: dbuf, one __syncthreads per K-step, stage-after-
// barrier, gload_lds w16, pre-swizzled source + XOR-swizzled ds_read.
// Epilogue: swapped operands; per-16-col fragment routed to Q/K (u16x4) or
// transposed Vt (scalar u16, 16-lane-contiguous t).
__global__ __launch_bounds__(512, 4) void gemm_qkv(const u16* __restrict__ Xb,
                                                   const u16* __restrict__ Wt,
                                                   u16* __restrict__ Qb,
                                                   u16* __restrict__ Vt) {
  const int id = blockIdx.x;            // 0..1023
  const int xcd = id & 7, j = id >> 3;  // j: 0..127
  const int bn = (xcd & 1) * 8 + (j & 7);        // 0..15
  const int bm = ((xcd >> 1) << 4) + (j >> 3);   // 0..63
  const int m0 = bm * 128, n0 = bn * 192;
  const int K = 1024;

  __shared__ u16 ldsA[2][8192];    // 128 x 64
  __shared__ u16 ldsB[2][12288];   // 192 x 64

  const int tid = threadIdx.x;          // 0..511
  const int lane = tid & 63;
  const int wid = tid >> 6;             // 0..7
  const int wm = wid >> 2, wn = wid & 3;
  const int l16 = lane & 15, lh = lane >> 4;
  const int strow = tid >> 3;                       // 0..63
  const int scol = ((tid & 7) ^ (strow & 7)) * 8;   // pre-swizzled source col
  const int rsw = l16 & 7;                          // read-side swizzle key

  f32x4 acc[4][3];
#pragma unroll
  for (int mi = 0; mi < 4; ++mi)
#pragma unroll
    for (int ni = 0; ni < 3; ++ni) acc[mi][ni] = (f32x4)(0.0f);

  auto stage = [&](int d, int k0) {
#pragma unroll
    for (int l = 0; l < 2; ++l)
      gload_lds16(Xb + (long)(m0 + l * 64 + strow) * K + k0 + scol,
                  &ldsA[d][l * 4096 + tid * 8]);
#pragma unroll
    for (int l = 0; l < 3; ++l)
      gload_lds16(Wt + (long)(n0 + l * 64 + strow) * K + k0 + scol,
                  &ldsB[d][l * 4096 + tid * 8]);
  };

  stage(0, 0);
  int cur = 0;
  for (int k0 = 0; k0 < K; k0 += 64) {
    __syncthreads();                          // buf[cur] ready; old readers done
    if (k0 + 64 < K) stage(cur ^ 1, k0 + 64); // lands during compute below
#pragma unroll
    for (int kk = 0; kk < 2; ++kk) {
      bf16x8 af[4], bfr[3];
#pragma unroll
      for (int mi = 0; mi < 4; ++mi)
        af[mi] = *reinterpret_cast<const bf16x8*>(
            &ldsA[cur][(wm * 64 + mi * 16 + l16) * 64 + (((kk * 4 + lh) ^ rsw)) * 8]);
#pragma unroll
      for (int ni = 0; ni < 3; ++ni)
        bfr[ni] = *reinterpret_cast<const bf16x8*>(
            &ldsB[cur][(wn * 48 + ni * 16 + l16) * 64 + (((kk * 4 + lh) ^ rsw)) * 8]);
#pragma unroll
      for (int mi = 0; mi < 4; ++mi)
#pragma unroll
        for (int ni = 0; ni < 3; ++ni)
          acc[mi][ni] = __builtin_amdgcn_mfma_f32_16x16x32_bf16(bfr[ni], af[mi], acc[mi][ni], 0, 0, 0);
    }
    cur ^= 1;
  }

  // Swapped layout: C[m0+wm*64+mi*16+l16][n0+wn*48+ni*16+lh*4+r] = acc[mi][ni][r]
  const int rowt = m0 + wm * 64 + l16;
#pragma unroll
  for (int ni = 0; ni < 3; ++ni) {
    const int gc0 = n0 + wn * 48 + ni * 16 + lh * 4;  // 16-col fragment never
    const int z = gc0 >> 10;                          // straddles a 1024 boundary
    const int lc = gc0 & 1023;
    if (z < 2) {
      u16* C = Qb + (long)z * 8388608;
#pragma unroll
      for (int mi = 0; mi < 4; ++mi) {
        u16x4 o;
#pragma unroll
        for (int r = 0; r < 4; ++r) o[r] = f2bf(acc[mi][ni][r]);
        *reinterpret_cast<u16x4*>(&C[(long)(rowt + mi * 16) * 1024 + lc]) = o;
      }
    } else {
      // V: Vt[b][e][t] = acc value at t = global row, e = lc + r.
#pragma unroll
      for (int mi = 0; mi < 4; ++mi) {
        const int grow = rowt + mi * 16;
        const int b = grow >> 11, t = grow & 2047;
#pragma unroll
        for (int r = 0; r < 4; ++r)
          Vt[(long)b * 2097152 + (long)(lc + r) * 2048 + t] = f2bf(acc[mi][ni][r]);
      }
    }
  }
}

// ---------------- NT GEMM core (r10 config): 128x128 tile, 8 waves ----------------
// MODE 1: P = exp(Q K^T) per batch. grid (16,16,4), skip bn>bm, bf16 + row sums.
// MODE 2: O = P V / rowsum per batch. grid (8,16,4), kEnd=m0+128, f32 out.
template <int MODE>
__global__ __launch_bounds__(512, 2) void gemm_nt(const u16* __restrict__ Ag,
                                                  const u16* __restrict__ Bg,
                                                  void* __restrict__ Cg,
                                                  float* __restrict__ Sums,
                                                  int K, long sA, long sB, long sC) {
  int bm, bn, bz;
  if constexpr (MODE == 1) {
    const int id = blockIdx.y * 16 + blockIdx.x;  // 0..255
    const int xcd = id & 7, j = id >> 3;
    bn = j & 15;
    bm = (j >> 4) ? (15 - xcd) : xcd;    // rows (x,15-x): balanced triangle
    bz = blockIdx.z;
    if (bn > bm) return;
  } else {
    const int id = blockIdx.y * 8 + blockIdx.x;   // 0..127
    const int xcd = id & 7, j = id >> 3;
    bn = j & 7;
    bm = (j >> 3) ? (15 - xcd) : xcd;    // balanced: work ∝ bm+1
    bz = blockIdx.z;
  }

  const u16* A = Ag + (long)bz * sA;
  const u16* B = Bg + (long)bz * sB;
  const int m0 = bm * 128, n0 = bn * 128;
  int kEnd = K;
  if constexpr (MODE == 2) kEnd = m0 + 128;  // causal k-limit

  __shared__ u16 ldsA[2][8192];
  __shared__ u16 ldsB[2][8192];

  const int tid = threadIdx.x;          // 0..511
  const int lane = tid & 63;
  const int wid = tid >> 6;             // 0..7
  const int wm = wid >> 2, wn = wid & 3;
  const int l16 = lane & 15, lh = lane >> 4;
  const int strow = tid >> 3;                       // 0..63
  const int scol = ((tid & 7) ^ (strow & 7)) * 8;   // pre-swizzled source column
  const int rsw = l16 & 7;                          // read-side swizzle key

  f32x4 acc[4][2];
#pragma unroll
  for (int mi = 0; mi < 4; ++mi)
#pragma unroll
    for (int ni = 0; ni < 2; ++ni) acc[mi][ni] = (f32x4)(0.0f);

  auto stage = [&](int d, int k0) {
#pragma unroll
    for (int l = 0; l < 2; ++l) {
      const int row = l * 64 + strow;   // 0..127
      gload_lds16(A + (long)(m0 + row) * K + k0 + scol, &ldsA[d][l * 4096 + tid * 8]);
      gload_lds16(B + (long)(n0 + row) * K + k0 + scol, &ldsB[d][l * 4096 + tid * 8]);
    }
  };

  stage(0, 0);
  int cur = 0;
  for (int k0 = 0; k0 < kEnd; k0 += 64) {
    __syncthreads();                         // buf[cur] ready; old readers done
    if (k0 + 64 < kEnd) stage(cur ^ 1, k0 + 64);  // lands during compute below
#pragma unroll
    for (int kk = 0; kk < 2; ++kk) {
      bf16x8 af[4], bfr[2];
#pragma unroll
      for (int mi = 0; mi < 4; ++mi)
        af[mi] = *reinterpret_cast<const bf16x8*>(
            &ldsA[cur][(wm * 64 + mi * 16 + l16) * 64 + (((kk * 4 + lh) ^ rsw)) * 8]);
#pragma unroll
      for (int ni = 0; ni < 2; ++ni)
        bfr[ni] = *reinterpret_cast<const bf16x8*>(
            &ldsB[cur][(wn * 32 + ni * 16 + l16) * 64 + (((kk * 4 + lh) ^ rsw)) * 8]);
#pragma unroll
      for (int mi = 0; mi < 4; ++mi)
#pragma unroll
        for (int ni = 0; ni < 2; ++ni)
          acc[mi][ni] = __builtin_amdgcn_mfma_f32_16x16x32_bf16(bfr[ni], af[mi], acc[mi][ni], 0, 0, 0);
    }
    cur ^= 1;
  }

  if constexpr (MODE == 1) {
    // P = exp(S), zero above diagonal; row sums from bf16-rounded values so
    // numerator/denominator agree. shfl over lh then 1 atomic per 16 lanes.
    u16* C = (u16*)Cg + (long)bz * sC;
    float* sums = Sums + (long)bz * 2048;
    const long rown = (long)(m0 + wm * 64 + l16);
    const int coln = n0 + wn * 32 + lh * 4;
#pragma unroll
    for (int mi = 0; mi < 4; ++mi) {
      const int gr = m0 + wm * 64 + l16 + mi * 16;
      float rs = 0.0f;
#pragma unroll
      for (int ni = 0; ni < 2; ++ni) {
        u16x4 o;
#pragma unroll
        for (int r = 0; r < 4; ++r) {
          const int gc = coln + ni * 16 + r;
          const float e = (gc <= gr) ? __expf(acc[mi][ni][r]) : 0.0f;
          const u16 ub = f2bf(e);
          o[r] = ub;
          rs += bf2f(ub);
        }
        *reinterpret_cast<u16x4*>(&C[(rown + mi * 16) * 2048 + coln + ni * 16]) = o;
      }
      rs += __shfl_xor(rs, 16);
      rs += __shfl_xor(rs, 32);
      if (lh == 0) atomicAdd(&sums[gr], rs);
    }
  } else {
    // O = acc / rowsum
    float* C = (float*)Cg + (long)bz * sC;
    const float* sums = Sums + (long)bz * 2048;
    const long rown = (long)(m0 + wm * 64 + l16);
    const int coln = n0 + wn * 32 + lh * 4;
#pragma unroll
    for (int mi = 0; mi < 4; ++mi) {
      const float inv = 1.0f / sums[(int)rown + mi * 16];
#pragma unroll
      for (int ni = 0; ni < 2; ++ni) {
        f32x4 v = acc[mi][ni] * inv;
        *reinterpret_cast<f32x4*>(&C[(rown + mi * 16) * 1024 + coln + ni * 16]) = v;
      }
    }
  }
}

extern "C" void kernel_launch(void* const* d_in, const int* in_sizes, int n_in,
                              void* d_out, int out_size, void* d_ws, size_t ws_size,
                              hipStream_t stream) {
  const float* X  = (const float*)d_in[0];
  const float* Wq = (const float*)d_in[1];
  const float* Wk = (const float*)d_in[2];
  const float* Wv = (const float*)d_in[3];

  // workspace layout (u16 elements)
  u16* Xb = (u16*)d_ws;                 // 8192*1024
  u16* Wt = Xb + 8388608;               // [3072][1024]; Wq rows pre-scaled 1/32
  u16* Qb = Wt + 3145728;               // 8192*1024 (K follows at Qb+8388608)
  u16* Kb = Qb + 8388608;               // 8192*1024
  u16* Vt = Kb + 8388608;               // [b][1024][2048]
  u16* S  = Vt + 8388608;               // [b][2048][2048] -> holds P = exp(scores)
  float* sums = (float*)(S + 16777216); // [b][2048] row sums (32 KB)

  hipMemsetAsync(sums, 0, 4 * 2048 * sizeof(float), stream);

  // cast X + transpose W (one dispatch)
  prep_kernel<<<4864, 256, 0, stream>>>(X, Wq, Wk, Wv, Xb, Wt);

  // fused QKV projection, 128x192 tile (V written transposed); 1024 blocks = 2 rounds
  gemm_qkv<<<1024, 512, 0, stream>>>(Xb, Wt, Qb, Vt);

  // P = exp(Q K^T) per batch (Q pre-scaled; causal zeros; row sums via atomics)
  gemm_nt<1><<<dim3(16, 16, 4), 512, 0, stream>>>(
      Qb, Kb, S, sums, 1024, 2097152L, 2097152L, 4194304L);

  // O = P V / rowsum per batch
  gemm_nt<2><<<dim3(8, 16, 4), 512, 0, stream>>>(
      S, Vt, (float*)d_out, sums, 2048, 4194304L, 2097152L, 2097152L);
}